// Round 9
// baseline (99.134 us; speedup 1.0000x reference)
//
#include <hip/hip_runtime.h>

#define B_ 4
#define S_ 4096
#define D_ 128

typedef short short8 __attribute__((ext_vector_type(8)));
typedef float f32x4 __attribute__((ext_vector_type(4)));
typedef unsigned short us4 __attribute__((ext_vector_type(4)));

__device__ __forceinline__ unsigned short f2b(float f) {
    unsigned u = __builtin_bit_cast(unsigned, f);
    u += 0x7fffu + ((u >> 16) & 1u);   // RNE
    return (unsigned short)(u >> 16);
}

// ---------------- kernel 1: W -> Wt bf16 [192][128], q-part pre-scaled by 1/8
__global__ void wtrans_k(const float* __restrict__ Wq, const float* __restrict__ Wk,
                         const float* __restrict__ Wv, unsigned short* __restrict__ Wt) {
    int idx = blockIdx.x * 256 + threadIdx.x;     // 0..24575
    int d = idx / 192;
    int c = idx % 192;
    const float* Wm = (c < 64) ? Wq : (c < 128) ? Wk : Wv;
    int cm = c & 63;
    float v = Wm[d * 64 + cm];
    if (c < 64) v *= 0.125f;                      // fold softmax 1/sqrt(64) into Q
    Wt[c * 128 + d] = f2b(v);
}

// ---------------- kernel 2: QKV projection (MFMA bf16) + input copy into out[:, :128]
__global__ __launch_bounds__(256) void proj_k(
    const float* __restrict__ inp, const unsigned short* __restrict__ Wt,
    const float* __restrict__ bq, const float* __restrict__ bk, const float* __restrict__ bv,
    unsigned short* __restrict__ Qb, unsigned short* __restrict__ Kb,
    unsigned short* __restrict__ Vt, float* __restrict__ out) {
    __shared__ unsigned short in_s[64 * 128];
    __shared__ unsigned short w_s[192 * 128];
    int tid = threadIdx.x;
    int b = blockIdx.x >> 6;
    int s0 = (blockIdx.x & 63) << 6;

    for (int r = 0; r < 4; ++r) {
        int u = r * 256 + tid;
        int s = u >> 4, seg = u & 15;
        const float* src = inp + ((size_t)(b * S_ + s0 + s) * D_ + seg * 8);
        float4 v0 = *(const float4*)src;
        float4 v1 = *(const float4*)(src + 4);
        float* dst = out + ((size_t)(b * S_ + s0 + s) * 192 + seg * 8);
        *(float4*)dst = v0;
        *(float4*)(dst + 4) = v1;
        unsigned short h[8] = {f2b(v0.x), f2b(v0.y), f2b(v0.z), f2b(v0.w),
                               f2b(v1.x), f2b(v1.y), f2b(v1.z), f2b(v1.w)};
        int phys = seg ^ (s & 7);
        *(uint4*)(&in_s[s * 128 + phys * 8]) = *(uint4*)h;
    }
    for (int r = 0; r < 12; ++r) {
        int u = r * 256 + tid;
        int c = u >> 4, seg = u & 15;
        uint4 w = *(const uint4*)(Wt + c * 128 + seg * 8);
        int phys = seg ^ (c & 7);
        *(uint4*)(&w_s[c * 128 + phys * 8]) = w;
    }
    __syncthreads();

    int lane = tid & 63, wid = tid >> 6;
    int lo = lane & 15, hi = lane >> 4;
    f32x4 acc[4][3];
    for (int i = 0; i < 4; ++i)
        for (int j = 0; j < 3; ++j) acc[i][j] = (f32x4)0.f;

    for (int kk = 0; kk < 4; ++kk) {
        int unit = kk * 4 + hi;
        short8 a[4], bf[3];
        for (int rt = 0; rt < 4; ++rt) {
            int s = rt * 16 + lo;
            a[rt] = *(const short8*)(&in_s[s * 128 + (unit ^ (s & 7)) * 8]);
        }
        for (int j = 0; j < 3; ++j) {
            int c = (wid * 3 + j) * 16 + lo;
            bf[j] = *(const short8*)(&w_s[c * 128 + (unit ^ (c & 7)) * 8]);
        }
        for (int rt = 0; rt < 4; ++rt)
            for (int j = 0; j < 3; ++j)
                acc[rt][j] = __builtin_amdgcn_mfma_f32_16x16x32_bf16(a[rt], bf[j], acc[rt][j], 0, 0, 0);
    }

    for (int j = 0; j < 3; ++j) {
        int c = (wid * 3 + j) * 16 + lo;
        float bias = (c < 64) ? bq[c] * 0.125f : (c < 128) ? bk[c - 64] : bv[c - 128];
        for (int rt = 0; rt < 4; ++rt) {
            int sbase = s0 + rt * 16 + hi * 4;
            if (c < 128) {
                unsigned short* dst = (c < 64) ? Qb : Kb;
                int cc = c & 63;
                for (int r = 0; r < 4; ++r)
                    dst[(size_t)(b * S_ + sbase + r) * 64 + cc] = f2b(acc[rt][j][r] + bias);
            } else {
                int dv = c - 128;
                us4 h;
                for (int r = 0; r < 4; ++r) h[r] = f2b(acc[rt][j][r] + bias);
                *(us4*)(&Vt[(size_t)(b * 64 + dv) * S_ + sbase]) = h;   // V transposed [dv][s]
            }
        }
    }
}

// ---------------- kernel 3: causal flash attention
// Proven R6/R8 wave code widened to 128 kv-cols per iteration (2 adjacent
// 64-chunks share ONE softmax round); flattened tile->block assignment so
// every CU's 4 resident blocks sum to constant work. LDS union: per-wave
// P bf16 [16][136] in-loop == per-seg O f32 [16][68] at publish (4352 B).
__global__ __launch_bounds__(512) void attn_k(
    const unsigned short* __restrict__ Qb, const unsigned short* __restrict__ Kb,
    const unsigned short* __restrict__ Vt, float* __restrict__ out) {
    __shared__ __align__(16) unsigned char un[8][4352];
    __shared__ float mbuf[8][16];
    __shared__ float lbuf[8][16];

    int tid = threadIdx.x;
    int bid = blockIdx.x;
    int b = bid & 3;
    // flattened assignment: CU's 4 co-resident blocks (g=0..3, same x) sum const
    int x = (bid >> 2) & 63;
    int g = bid >> 8;
    int xx = (g & 1) ? (63 - x) : x;
    int t = 255 - 64 * g - xx;
    int lane = tid & 63, seg = tid >> 6;        // 8 waves = 8 KV segments
    int lo = lane & 15, hi = lane >> 4;
    int q0 = t << 4;
    int n2 = (q0 + 16 + 127) >> 7;              // number of 128-wide kv chunks
    unsigned short* pls = (unsigned short*)&un[seg][0];   // [16 q][136] bf16 P

    // Q fragments (pre-scaled by 1/8 in projection)
    short8 qf[2];
    {
        const unsigned short* qp = Qb + (size_t)(b * S_ + q0 + lo) * 64 + hi * 8;
        qf[0] = *(const short8*)(qp);
        qf[1] = *(const short8*)(qp + 32);
    }

    f32x4 o[4];
    for (int i = 0; i < 4; ++i) o[i] = (f32x4)0.f;
    f32x4 m4 = (f32x4)(-3e38f), l4 = (f32x4)0.f;

    for (int c = seg; c < n2; c += 8) {
        int kv0 = c << 7;                       // 128-wide chunk base
        // ---- QK^T for 8 kv-subtiles (two 64-halves), K straight from L2
        f32x4 sc[8];
        for (int kvt = 0; kvt < 8; ++kvt) {
            sc[kvt] = (f32x4)0.f;
            const unsigned short* kp = Kb + (size_t)(b * S_ + kv0 + kvt * 16 + lo) * 64 + hi * 8;
            short8 kf0 = *(const short8*)(kp);
            short8 kf1 = *(const short8*)(kp + 32);
            sc[kvt] = __builtin_amdgcn_mfma_f32_16x16x32_bf16(qf[0], kf0, sc[kvt], 0, 0, 0);
            sc[kvt] = __builtin_amdgcn_mfma_f32_16x16x32_bf16(qf[1], kf1, sc[kvt], 0, 0, 0);
        }
        // ---- causal mask (only near/above diagonal)
        if (kv0 + 127 > q0) {
            for (int kvt = 0; kvt < 8; ++kvt)
                for (int r = 0; r < 4; ++r) {
                    int kvg = kv0 + kvt * 16 + lo;
                    int qg = q0 + hi * 4 + r;
                    if (kvg > qg) sc[kvt][r] = -3e38f;
                }
        }
        // ---- ONE online-softmax round per 128 cols; rows = hi*4+r
        f32x4 mx, t1, t2, t3;
        for (int r = 0; r < 4; ++r) {
            mx[r] = fmaxf(sc[0][r], sc[1][r]);
            t1[r] = fmaxf(sc[2][r], sc[3][r]);
            t2[r] = fmaxf(sc[4][r], sc[5][r]);
            t3[r] = fmaxf(sc[6][r], sc[7][r]);
        }
        for (int r = 0; r < 4; ++r)
            mx[r] = fmaxf(fmaxf(mx[r], t1[r]), fmaxf(t2[r], t3[r]));
        for (int off = 1; off < 16; off <<= 1)
            for (int r = 0; r < 4; ++r) mx[r] = fmaxf(mx[r], __shfl_xor(mx[r], off));
        f32x4 mn, fac;
        for (int r = 0; r < 4; ++r) {
            mn[r] = fmaxf(m4[r], mx[r]);
            fac[r] = __expf(m4[r] - mn[r]);
        }
        f32x4 rs = (f32x4)0.f;
        for (int kvt = 0; kvt < 8; ++kvt)
            for (int r = 0; r < 4; ++r) {
                // guards rows whose first-seen chunk is fully masked
                float p = (sc[kvt][r] > -1e37f) ? __expf(sc[kvt][r] - mn[r]) : 0.f;
                sc[kvt][r] = p;
                rs[r] += p;
            }
        for (int off = 1; off < 16; off <<= 1)
            for (int r = 0; r < 4; ++r) rs[r] += __shfl_xor(rs[r], off);
        for (int r = 0; r < 4; ++r) {
            l4[r] = l4[r] * fac[r] + rs[r];
            m4[r] = mn[r];
        }
        for (int d = 0; d < 4; ++d)
            for (int r = 0; r < 4; ++r) o[d][r] *= fac[r];
        // ---- P -> per-wave LDS (bf16, scalar stores; [16 q][136], cols 0..127)
        for (int kvt = 0; kvt < 8; ++kvt)
            for (int r = 0; r < 4; ++r)
                pls[(hi * 4 + r) * 136 + kvt * 16 + lo] = f2b(sc[kvt][r]);
        short8 pa[4];
        for (int kk = 0; kk < 4; ++kk)
            pa[kk] = *(const short8*)(&pls[lo * 136 + kk * 32 + hi * 8]);
        // ---- PV from global V^T: O[q][dv] += P[q][kv] * V^T[dv][kv]
        for (int d = 0; d < 4; ++d) {
            const unsigned short* vp = Vt + (size_t)(b * 64 + d * 16 + lo) * S_ + kv0 + hi * 8;
            for (int kk = 0; kk < 4; ++kk) {
                short8 vf = *(const short8*)(vp + kk * 32);
                o[d] = __builtin_amdgcn_mfma_f32_16x16x32_bf16(pa[kk], vf, o[d], 0, 0, 0);
            }
        }
    }

    // barrier: all waves done with P region; orders short-loads above against
    // float-stores below (full fence, TBAA-proof)
    __syncthreads();

    // ---- publish segment partials into the unioned region as [q][68] f32
    if (lo == 0) {
        for (int r = 0; r < 4; ++r) {
            mbuf[seg][hi * 4 + r] = m4[r];
            lbuf[seg][hi * 4 + r] = l4[r];
        }
    }
    {
        float* obs = (float*)&un[seg][0];
        for (int d = 0; d < 4; ++d)
            for (int r = 0; r < 4; ++r)
                obs[(hi * 4 + r) * 68 + d * 16 + lo] = o[d][r];
    }
    __syncthreads();

    // ---- merge 8 segments; write out[:, 128:192]
    {
        int q = tid >> 5;                   // 0..15
        int dv0 = (tid & 31) * 2;           // 0..62
        float M = mbuf[0][q];
        for (int s = 1; s < 8; ++s) M = fmaxf(M, mbuf[s][q]);
        float L = 0.f, a0 = 0.f, a1 = 0.f;
        for (int s = 0; s < 8; ++s) {
            float w = __expf(mbuf[s][q] - M);
            const float* obS = (const float*)&un[s][0];
            L += w * lbuf[s][q];
            a0 += w * obS[q * 68 + dv0];
            a1 += w * obS[q * 68 + dv0 + 1];
        }
        float inv = 1.f / L;
        float2 res;
        res.x = a0 * inv;
        res.y = a1 * inv;
        *(float2*)(&out[(size_t)(b * S_ + q0 + q) * 192 + 128 + dv0]) = res;
    }
}

extern "C" void kernel_launch(void* const* d_in, const int* in_sizes, int n_in,
                              void* d_out, int out_size, void* d_ws, size_t ws_size,
                              hipStream_t stream) {
    const float* inp = (const float*)d_in[0];
    const float* Wq  = (const float*)d_in[1];
    const float* bq  = (const float*)d_in[2];
    const float* Wk  = (const float*)d_in[3];
    const float* bk  = (const float*)d_in[4];
    const float* Wv  = (const float*)d_in[5];
    const float* bv  = (const float*)d_in[6];
    float* out = (float*)d_out;

    char* ws = (char*)d_ws;
    unsigned short* Wt = (unsigned short*)ws;                          // 48 KiB
    unsigned short* Qb = (unsigned short*)(ws + 49152);                // 2 MiB
    unsigned short* Kb = (unsigned short*)(ws + 49152 + 2097152);      // 2 MiB
    unsigned short* Vt = (unsigned short*)(ws + 49152 + 2 * 2097152);  // 2 MiB (transposed)

    wtrans_k<<<96, 256, 0, stream>>>(Wq, Wk, Wv, Wt);
    proj_k<<<256, 256, 0, stream>>>(inp, Wt, bq, bk, bv, Qb, Kb, Vt, out);
    attn_k<<<1024, 512, 0, stream>>>(Qb, Kb, Vt, out);
}

// Round 10
// 84.227 us; speedup vs baseline: 1.1770x; 1.1770x over previous
//
#include <hip/hip_runtime.h>

#define B_ 4
#define S_ 4096
#define D_ 128

typedef short short8 __attribute__((ext_vector_type(8)));
typedef float f32x4 __attribute__((ext_vector_type(4)));
typedef unsigned short us4 __attribute__((ext_vector_type(4)));

__device__ __forceinline__ unsigned short f2b(float f) {
    unsigned u = __builtin_bit_cast(unsigned, f);
    u += 0x7fffu + ((u >> 16) & 1u);   // RNE
    return (unsigned short)(u >> 16);
}

// ---------------- kernel 1: W -> Wt bf16 [192][128], q-part pre-scaled by 1/8
__global__ void wtrans_k(const float* __restrict__ Wq, const float* __restrict__ Wk,
                         const float* __restrict__ Wv, unsigned short* __restrict__ Wt) {
    int idx = blockIdx.x * 256 + threadIdx.x;     // 0..24575
    int d = idx / 192;
    int c = idx % 192;
    const float* Wm = (c < 64) ? Wq : (c < 128) ? Wk : Wv;
    int cm = c & 63;
    float v = Wm[d * 64 + cm];
    if (c < 64) v *= 0.125f;                      // fold softmax 1/sqrt(64) into Q
    Wt[c * 128 + d] = f2b(v);
}

// ---------------- kernel 2: QKV projection (MFMA bf16) + input copy into out[:, :128]
__global__ __launch_bounds__(256) void proj_k(
    const float* __restrict__ inp, const unsigned short* __restrict__ Wt,
    const float* __restrict__ bq, const float* __restrict__ bk, const float* __restrict__ bv,
    unsigned short* __restrict__ Qb, unsigned short* __restrict__ Kb,
    unsigned short* __restrict__ Vt, float* __restrict__ out) {
    __shared__ unsigned short in_s[64 * 128];
    __shared__ unsigned short w_s[192 * 128];
    int tid = threadIdx.x;
    int b = blockIdx.x >> 6;
    int s0 = (blockIdx.x & 63) << 6;

    for (int r = 0; r < 4; ++r) {
        int u = r * 256 + tid;
        int s = u >> 4, seg = u & 15;
        const float* src = inp + ((size_t)(b * S_ + s0 + s) * D_ + seg * 8);
        float4 v0 = *(const float4*)src;
        float4 v1 = *(const float4*)(src + 4);
        float* dst = out + ((size_t)(b * S_ + s0 + s) * 192 + seg * 8);
        *(float4*)dst = v0;
        *(float4*)(dst + 4) = v1;
        unsigned short h[8] = {f2b(v0.x), f2b(v0.y), f2b(v0.z), f2b(v0.w),
                               f2b(v1.x), f2b(v1.y), f2b(v1.z), f2b(v1.w)};
        int phys = seg ^ (s & 7);
        *(uint4*)(&in_s[s * 128 + phys * 8]) = *(uint4*)h;
    }
    for (int r = 0; r < 12; ++r) {
        int u = r * 256 + tid;
        int c = u >> 4, seg = u & 15;
        uint4 w = *(const uint4*)(Wt + c * 128 + seg * 8);
        int phys = seg ^ (c & 7);
        *(uint4*)(&w_s[c * 128 + phys * 8]) = w;
    }
    __syncthreads();

    int lane = tid & 63, wid = tid >> 6;
    int lo = lane & 15, hi = lane >> 4;
    f32x4 acc[4][3];
    for (int i = 0; i < 4; ++i)
        for (int j = 0; j < 3; ++j) acc[i][j] = (f32x4)0.f;

    for (int kk = 0; kk < 4; ++kk) {
        int unit = kk * 4 + hi;
        short8 a[4], bf[3];
        for (int rt = 0; rt < 4; ++rt) {
            int s = rt * 16 + lo;
            a[rt] = *(const short8*)(&in_s[s * 128 + (unit ^ (s & 7)) * 8]);
        }
        for (int j = 0; j < 3; ++j) {
            int c = (wid * 3 + j) * 16 + lo;
            bf[j] = *(const short8*)(&w_s[c * 128 + (unit ^ (c & 7)) * 8]);
        }
        for (int rt = 0; rt < 4; ++rt)
            for (int j = 0; j < 3; ++j)
                acc[rt][j] = __builtin_amdgcn_mfma_f32_16x16x32_bf16(a[rt], bf[j], acc[rt][j], 0, 0, 0);
    }

    for (int j = 0; j < 3; ++j) {
        int c = (wid * 3 + j) * 16 + lo;
        float bias = (c < 64) ? bq[c] * 0.125f : (c < 128) ? bk[c - 64] : bv[c - 128];
        for (int rt = 0; rt < 4; ++rt) {
            int sbase = s0 + rt * 16 + hi * 4;
            if (c < 128) {
                unsigned short* dst = (c < 64) ? Qb : Kb;
                int cc = c & 63;
                for (int r = 0; r < 4; ++r)
                    dst[(size_t)(b * S_ + sbase + r) * 64 + cc] = f2b(acc[rt][j][r] + bias);
            } else {
                int dv = c - 128;
                us4 h;
                for (int r = 0; r < 4; ++r) h[r] = f2b(acc[rt][j][r] + bias);
                *(us4*)(&Vt[(size_t)(b * 64 + dv) * S_ + sbase]) = h;   // V transposed [dv][s]
            }
        }
    }
}

// ---------------- kernel 3: causal flash attention
// R8 structure (1024 blocks, one 16-row tile, descending t; 8 KV-segment
// waves; LDS union P/O). R10 delta: ALL 16 K/V fragment loads of an
// iteration are issued up-front into registers (explicit MLP) so the
// ~400-cycle L2 latencies overlap instead of serializing into the chain.
__global__ __launch_bounds__(512) void attn_k(
    const unsigned short* __restrict__ Qb, const unsigned short* __restrict__ Kb,
    const unsigned short* __restrict__ Vt, float* __restrict__ out) {
    __shared__ __align__(16) unsigned char un[8][4352];
    __shared__ float mbuf[8][16];
    __shared__ float lbuf[8][16];

    int tid = threadIdx.x;
    int b = blockIdx.x & 3;
    int t = 255 - (blockIdx.x >> 2);            // descending tile size (LPT)
    int lane = tid & 63, seg = tid >> 6;        // 8 waves = 8 KV segments
    int lo = lane & 15, hi = lane >> 4;
    int q0 = t << 4;
    int n_w = (q0 + 79) >> 6;                   // causal 64-chunk count for rows q0..q0+15
    unsigned short* pls = (unsigned short*)&un[seg][0];   // [16 q][72] bf16 P

    // Q fragments (pre-scaled by 1/8 in projection)
    short8 qf[2];
    {
        const unsigned short* qp = Qb + (size_t)(b * S_ + q0 + lo) * 64 + hi * 8;
        qf[0] = *(const short8*)(qp);
        qf[1] = *(const short8*)(qp + 32);
    }

    f32x4 o[4];
    for (int i = 0; i < 4; ++i) o[i] = (f32x4)0.f;
    f32x4 m4 = (f32x4)(-3e38f), l4 = (f32x4)0.f;

    for (int c = seg; c < n_w; c += 8) {
        int kv0 = c << 6;
        // ---- issue ALL K and V fragment loads up-front (16 independent L2 hits)
        const unsigned short* kbase = Kb + (size_t)(b * S_ + kv0 + lo) * 64 + hi * 8;
        const unsigned short* vbase = Vt + (size_t)(b * 64 + lo) * S_ + kv0 + hi * 8;
        short8 kf0[4], kf1[4], vf0[4], vf1[4];
#pragma unroll
        for (int kvt = 0; kvt < 4; ++kvt) {
            kf0[kvt] = *(const short8*)(kbase + kvt * 1024);        // +kvt*16 rows
            kf1[kvt] = *(const short8*)(kbase + kvt * 1024 + 32);
        }
#pragma unroll
        for (int d = 0; d < 4; ++d) {
            vf0[d] = *(const short8*)(vbase + (size_t)d * 16 * S_);
            vf1[d] = *(const short8*)(vbase + (size_t)d * 16 * S_ + 32);
        }
        // ---- QK^T
        f32x4 sc[4];
#pragma unroll
        for (int kvt = 0; kvt < 4; ++kvt) {
            sc[kvt] = (f32x4)0.f;
            sc[kvt] = __builtin_amdgcn_mfma_f32_16x16x32_bf16(qf[0], kf0[kvt], sc[kvt], 0, 0, 0);
            sc[kvt] = __builtin_amdgcn_mfma_f32_16x16x32_bf16(qf[1], kf1[kvt], sc[kvt], 0, 0, 0);
        }
        // ---- causal mask (only near diagonal)
        if (kv0 + 63 > q0) {
            for (int kvt = 0; kvt < 4; ++kvt)
                for (int r = 0; r < 4; ++r) {
                    int kvg = kv0 + kvt * 16 + lo;
                    int qg = q0 + hi * 4 + r;
                    if (kvg > qg) sc[kvt][r] = -3e38f;
                }
        }
        // ---- online softmax; rows = hi*4+r, 16 cols across lo lanes
        f32x4 mx;
        for (int r = 0; r < 4; ++r)
            mx[r] = fmaxf(fmaxf(sc[0][r], sc[1][r]), fmaxf(sc[2][r], sc[3][r]));
        for (int off = 1; off < 16; off <<= 1)
            for (int r = 0; r < 4; ++r) mx[r] = fmaxf(mx[r], __shfl_xor(mx[r], off));
        f32x4 mn, fac;
        for (int r = 0; r < 4; ++r) {
            mn[r] = fmaxf(m4[r], mx[r]);
            fac[r] = __expf(m4[r] - mn[r]);
        }
        f32x4 rs = (f32x4)0.f;
        for (int kvt = 0; kvt < 4; ++kvt)
            for (int r = 0; r < 4; ++r) {
                // guards rows whose first-seen chunk is fully masked
                float p = (sc[kvt][r] > -1e37f) ? __expf(sc[kvt][r] - mn[r]) : 0.f;
                sc[kvt][r] = p;
                rs[r] += p;
            }
        for (int off = 1; off < 16; off <<= 1)
            for (int r = 0; r < 4; ++r) rs[r] += __shfl_xor(rs[r], off);
        for (int r = 0; r < 4; ++r) {
            l4[r] = l4[r] * fac[r] + rs[r];
            m4[r] = mn[r];
        }
        for (int d = 0; d < 4; ++d)
            for (int r = 0; r < 4; ++r) o[d][r] *= fac[r];
        // ---- P -> per-wave LDS (bf16, scalar stores), transpose read
        for (int kvt = 0; kvt < 4; ++kvt)
            for (int r = 0; r < 4; ++r)
                pls[(hi * 4 + r) * 72 + kvt * 16 + lo] = f2b(sc[kvt][r]);
        short8 pa[2];
        for (int kk = 0; kk < 2; ++kk)
            pa[kk] = *(const short8*)(&pls[lo * 72 + kk * 32 + hi * 8]);
        // ---- PV from pre-loaded V registers
#pragma unroll
        for (int d = 0; d < 4; ++d) {
            o[d] = __builtin_amdgcn_mfma_f32_16x16x32_bf16(pa[0], vf0[d], o[d], 0, 0, 0);
            o[d] = __builtin_amdgcn_mfma_f32_16x16x32_bf16(pa[1], vf1[d], o[d], 0, 0, 0);
        }
    }

    // barrier: all waves done with P region; orders short-loads above against
    // float-stores below (full fence, TBAA-proof)
    __syncthreads();

    // ---- publish segment partials into the unioned region as [q][68] f32
    if (lo == 0) {
        for (int r = 0; r < 4; ++r) {
            mbuf[seg][hi * 4 + r] = m4[r];
            lbuf[seg][hi * 4 + r] = l4[r];
        }
    }
    {
        float* obs = (float*)&un[seg][0];
        for (int d = 0; d < 4; ++d)
            for (int r = 0; r < 4; ++r)
                obs[(hi * 4 + r) * 68 + d * 16 + lo] = o[d][r];
    }
    __syncthreads();

    // ---- merge 8 segments; write out[:, 128:192]
    {
        int q = tid >> 5;                   // 0..15
        int dv0 = (tid & 31) * 2;           // 0..62
        float M = mbuf[0][q];
        for (int s = 1; s < 8; ++s) M = fmaxf(M, mbuf[s][q]);
        float L = 0.f, a0 = 0.f, a1 = 0.f;
        for (int s = 0; s < 8; ++s) {
            float w = __expf(mbuf[s][q] - M);
            const float* obS = (const float*)&un[s][0];
            L += w * lbuf[s][q];
            a0 += w * obS[q * 68 + dv0];
            a1 += w * obS[q * 68 + dv0 + 1];
        }
        float inv = 1.f / L;
        float2 res;
        res.x = a0 * inv;
        res.y = a1 * inv;
        *(float2*)(&out[(size_t)(b * S_ + q0 + q) * 192 + 128 + dv0]) = res;
    }
}

extern "C" void kernel_launch(void* const* d_in, const int* in_sizes, int n_in,
                              void* d_out, int out_size, void* d_ws, size_t ws_size,
                              hipStream_t stream) {
    const float* inp = (const float*)d_in[0];
    const float* Wq  = (const float*)d_in[1];
    const float* bq  = (const float*)d_in[2];
    const float* Wk  = (const float*)d_in[3];
    const float* bk  = (const float*)d_in[4];
    const float* Wv  = (const float*)d_in[5];
    const float* bv  = (const float*)d_in[6];
    float* out = (float*)d_out;

    char* ws = (char*)d_ws;
    unsigned short* Wt = (unsigned short*)ws;                          // 48 KiB
    unsigned short* Qb = (unsigned short*)(ws + 49152);                // 2 MiB
    unsigned short* Kb = (unsigned short*)(ws + 49152 + 2097152);      // 2 MiB
    unsigned short* Vt = (unsigned short*)(ws + 49152 + 2 * 2097152);  // 2 MiB (transposed)

    wtrans_k<<<96, 256, 0, stream>>>(Wq, Wk, Wv, Wt);
    proj_k<<<256, 256, 0, stream>>>(inp, Wt, bq, bk, bv, Qb, Kb, Vt, out);
    attn_k<<<1024, 512, 0, stream>>>(Qb, Kb, Vt, out);
}